// Round 6
// baseline (122.942 us; speedup 1.0000x reference)
//
#include <hip/hip_runtime.h>
#include <hip/hip_bf16.h>
#include <stdint.h>

#define BB 4
#define NN 4096
#define DD 128
#define BK 128

typedef __attribute__((ext_vector_type(8))) short short8;
typedef __attribute__((ext_vector_type(4))) float f32x4;

static __device__ __forceinline__ unsigned short f2bf(float f) {
  unsigned u = __builtin_bit_cast(unsigned, f);
  u += 0x7fffu + ((u >> 16) & 1u);   // round-to-nearest-even
  return (unsigned short)(u >> 16);
}

// ---------------- kernel 1: deg -> dinv (block-per-row) ----------------
__global__ __launch_bounds__(256) void k_deg(const float* __restrict__ A,
                                             float* __restrict__ dinv) {
  const int row = blockIdx.x;                 // b*N + n
  const float* a = A + (size_t)row * NN;
  float s = 0.f;
  for (int i = threadIdx.x * 4; i < NN; i += 256 * 4) {
    const float4 v = *reinterpret_cast<const float4*>(a + i);
    s += (v.x + v.y) + (v.z + v.w);
  }
  for (int off = 32; off > 0; off >>= 1) s += __shfl_down(s, off, 64);
  __shared__ float red[4];
  if ((threadIdx.x & 63) == 0) red[threadIdx.x >> 6] = s;
  __syncthreads();
  if (threadIdx.x == 0) {
    const float deg = (red[0] + red[1]) + (red[2] + red[3]) + 1.0f;
    dinv[row] = 1.0f / sqrtf(deg);
  }
}

// ---------------- kernel 2: Yt[b][d][m] = bf16(dinv[m] * X[b][m][d]) ----------------
__global__ __launch_bounds__(256) void k_prep(const float* __restrict__ X,
                                              const float* __restrict__ dinv,
                                              unsigned short* __restrict__ Yt) {
  __shared__ unsigned short tile[64][130];
  const int b = blockIdx.x >> 6;
  const int m0 = (blockIdx.x & 63) << 6;
  const float* Xb = X + ((size_t)b * NN + m0) * DD;
  const float* dv = dinv + b * NN + m0;
  for (int idx = threadIdx.x; idx < 64 * 128; idx += 256) {
    const int mi = idx >> 7, d = idx & 127;
    tile[mi][d] = f2bf(Xb[mi * DD + d] * dv[mi]);
  }
  __syncthreads();
  for (int idx = threadIdx.x; idx < 128 * 64; idx += 256) {
    const int d = idx >> 6, j = idx & 63;
    Yt[((size_t)b * DD + d) * NN + m0 + j] = tile[j][d];
  }
}

// ---------------- kernel 3: W -> bf16 ----------------
__global__ __launch_bounds__(256) void k_w(const float* __restrict__ W,
                                           unsigned short* __restrict__ Wb) {
  int idx = blockIdx.x * 1024 + threadIdx.x;
  for (int k = 0; k < 4; ++k, idx += 256) Wb[idx] = f2bf(W[idx]);
}

// ---------------- kernel 4: fused  out = dn*(A@Y + dn*X) @ W^T + b ----------------
// BM=64(n) x BN=128(d), BK=128(m). 8 waves (2x4), wave tile 32x32.
// One barrier per K-step. LDS 2 x {A[64][256B], B[128][256B]} = 96 KB.
// 16B-granule XOR swizzle: phys_slot = g ^ (row & 15) on 256B rows.
__global__ __launch_bounds__(512) void k_main(const float* __restrict__ A,
                                              const unsigned short* __restrict__ Yt,
                                              const unsigned short* __restrict__ Wb,
                                              const float* __restrict__ X,
                                              const float* __restrict__ dinv,
                                              const float* __restrict__ bias,
                                              float* __restrict__ out) {
  __shared__ char lds[98304];                  // buf k at k*49152: A @ +0, B @ +16384

  const int tid = threadIdx.x;
  const int l   = tid & 63;
  const int wid = tid >> 6;
  const int b   = blockIdx.x >> 6;
  const int n0  = (blockIdx.x & 63) << 6;
  const int wr  = wid >> 2;     // 0..1
  const int wc  = wid & 3;      // 0..3

  const float* Ab = A + (size_t)(b * NN + n0) * NN;
  const unsigned short* Ytb = Yt + (size_t)b * DD * NN;

  // ---- A staging: 16 f32/thread -> 2 swizzled ds_write_b128
  const int sar = tid >> 3;                    // row 0..63
  const int sg0 = (tid & 7) << 1;              // granule pair 0,2,..,14
  const float* pA = Ab + (size_t)sar * NN + (sg0 << 3);
  float4 ra[4];
  auto LOADA = [&](int t) {
#pragma unroll
    for (int i = 0; i < 4; ++i)
      ra[i] = *reinterpret_cast<const float4*>(pA + t * BK + i * 4);
  };
  auto CVTA = [&](int nb) {
    char* As = lds + nb * 49152 + sar * 256;
#pragma unroll
    for (int j = 0; j < 2; ++j) {
      short8 v;
      v[0] = (short)f2bf(ra[2*j].x);   v[1] = (short)f2bf(ra[2*j].y);
      v[2] = (short)f2bf(ra[2*j].z);   v[3] = (short)f2bf(ra[2*j].w);
      v[4] = (short)f2bf(ra[2*j+1].x); v[5] = (short)f2bf(ra[2*j+1].y);
      v[6] = (short)f2bf(ra[2*j+1].z); v[7] = (short)f2bf(ra[2*j+1].w);
      *reinterpret_cast<short8*>(As + (((sg0 + j) ^ (sar & 15)) << 4)) = v;
    }
  };

  // ---- B/W staging: 32KB [128][256B] tile, 4 global_load_lds per wave.
  // linear LDS dest (wave base + lane*16); source pre-swizzled so that
  // phys slot s at row r holds logical granule s ^ (r & 15).
  const int glrow4 = l >> 4;                   // 0..3
  const int glslot = l & 15;
  auto GLDS = [&](const unsigned short* src, int rstride, int colh, char* dstBase) {
#pragma unroll
    for (int i = 0; i < 4; ++i) {
      const int rloc = wid * 16 + i * 4 + glrow4;
      const int g = glslot ^ ((i * 4 + glrow4) & 15);
      __builtin_amdgcn_global_load_lds(src + (size_t)rloc * rstride + colh + g * 8,
                                       dstBase + (wid * 16 + i * 4) * 256, 16, 0, 0);
    }
  };

  // ---- fragments
  const int lrow = l & 15;
  const int lg   = l >> 4;
  const int ar0 = wr * 32 + lrow, ar1 = ar0 + 16;
  const int br0 = wc * 32 + lrow, br1 = br0 + 16;

  f32x4 acc[2][2] = {};
  auto GEMMSTEP = [&](int nb, f32x4 (&ac)[2][2]) {
    const char* Ap = lds + nb * 49152;
    const char* Bp = Ap + 16384;
#pragma unroll
    for (int kc = 0; kc < 4; ++kc) {
      const int g = kc * 4 + lg;
      const short8 a0 = *reinterpret_cast<const short8*>(Ap + ar0 * 256 + ((g ^ (ar0 & 15)) << 4));
      const short8 a1 = *reinterpret_cast<const short8*>(Ap + ar1 * 256 + ((g ^ (ar1 & 15)) << 4));
      const short8 b0 = *reinterpret_cast<const short8*>(Bp + br0 * 256 + ((g ^ (br0 & 15)) << 4));
      const short8 b1 = *reinterpret_cast<const short8*>(Bp + br1 * 256 + ((g ^ (br1 & 15)) << 4));
      ac[0][0] = __builtin_amdgcn_mfma_f32_16x16x32_bf16(a0, b0, ac[0][0], 0, 0, 0);
      ac[0][1] = __builtin_amdgcn_mfma_f32_16x16x32_bf16(a0, b1, ac[0][1], 0, 0, 0);
      ac[1][0] = __builtin_amdgcn_mfma_f32_16x16x32_bf16(a1, b0, ac[1][0], 0, 0, 0);
      ac[1][1] = __builtin_amdgcn_mfma_f32_16x16x32_bf16(a1, b1, ac[1][1], 0, 0, 0);
    }
  };

  // ---- prologue: buf0 <- t=0, buf1 <- t=1
  LOADA(0);
  GLDS(Ytb, NN, 0, lds + 16384);
  asm volatile("s_waitcnt vmcnt(4)" ::: "memory");       // A0 regs ready
  CVTA(0);
  LOADA(1);
  GLDS(Ytb, NN, BK, lds + 49152 + 16384);
  asm volatile("s_waitcnt vmcnt(8) lgkmcnt(0)" ::: "memory");  // B0 landed, A0 writes done
  __builtin_amdgcn_s_barrier();

  const int NT = NN / BK;                      // 32
  for (int t = 0; t < NT; ++t) {
    const int cur = t & 1;
    asm volatile("s_waitcnt vmcnt(4)" ::: "memory");     // A(t+1) regs ready (B(t+1) in flight)
    CVTA(cur ^ 1);                             // A(t+1) -> other buf
    GEMMSTEP(cur, acc);                        // compute current buf
    asm volatile("s_waitcnt vmcnt(0) lgkmcnt(0)" ::: "memory");  // B(t+1) landed + writes done
    __builtin_amdgcn_s_barrier();              // publish buf cur^1; release buf cur
    const int tn = (t + 2 < NT) ? t + 2 : NT - 1;        // clamped tail (uniform vm counts)
    LOADA(tn);
    GLDS(Ytb, NN, tn * BK, lds + cur * 49152 + 16384);
  }

  // ---- epilogue part 1: H = dn*(acc + dn*X) -> bf16 -> buf0 A-slot
  const int rg = lg << 2;
  const float* Xb  = X + (size_t)(b * NN + n0) * DD;
  const float* dvb = dinv + b * NN + n0;
#pragma unroll
  for (int mi = 0; mi < 2; ++mi)
#pragma unroll
    for (int r = 0; r < 4; ++r) {
      const int nl = wr * 32 + mi * 16 + rg + r;
      const float dn = dvb[nl];
#pragma unroll
      for (int ni = 0; ni < 2; ++ni) {
        const int d = wc * 32 + ni * 16 + lrow;
        const float h = dn * (acc[mi][ni][r] + dn * Xb[nl * DD + d]);
        *reinterpret_cast<unsigned short*>(
            lds + nl * 256 + (((d >> 3) ^ (nl & 15)) << 4) + (d & 7) * 2) = f2bf(h);
      }
    }
  GLDS(Wb, DD, 0, lds + 16384);                // W -> buf0 B-slot
  asm volatile("s_waitcnt vmcnt(0) lgkmcnt(0)" ::: "memory");  // W + stragglers + H writes
  __builtin_amdgcn_s_barrier();

  // ---- epilogue part 2: out = H @ W^T + bias  (K = D = 128, one step)
  f32x4 acc2[2][2] = {};
  GEMMSTEP(0, acc2);

  float* outb = out + (size_t)(b * NN + n0) * DD;
#pragma unroll
  for (int ni = 0; ni < 2; ++ni) {
    const int o = wc * 32 + ni * 16 + lrow;
    const float bo = bias[o];
#pragma unroll
    for (int mi = 0; mi < 2; ++mi)
#pragma unroll
      for (int r = 0; r < 4; ++r) {
        const int nl = wr * 32 + mi * 16 + rg + r;
        outb[(size_t)nl * DD + o] = acc2[mi][ni][r] + bo;
      }
  }
}

// ---------------- host ----------------
extern "C" void kernel_launch(void* const* d_in, const int* in_sizes, int n_in,
                              void* d_out, int out_size, void* d_ws, size_t ws_size,
                              hipStream_t stream) {
  const float* X    = (const float*)d_in[0];
  const float* A    = (const float*)d_in[1];
  const float* W    = (const float*)d_in[2];
  const float* bias = (const float*)d_in[3];
  float* out = (float*)d_out;

  char* ws = (char*)d_ws;
  float* dinv = (float*)ws;                                           // 64 KB
  unsigned short* Yt = (unsigned short*)(ws + 65536);                 // 4 MB
  unsigned short* Wb = Yt + (size_t)BB * DD * NN;                     // 32 KB

  k_deg <<<BB * NN, 256, 0, stream>>>(A, dinv);
  k_w   <<<16, 256, 0, stream>>>(W, Wb);
  k_prep<<<BB * (NN / 64), 256, 0, stream>>>(X, dinv, Yt);
  k_main<<<BB * (NN / 64), 512, 0, stream>>>(A, Yt, Wb, X, dinv, bias, out);
}